// Round 14
// baseline (175.000 us; speedup 1.0000x reference)
//
#include <hip/hip_runtime.h>
#include <hip/hip_bf16.h>
#include <math.h>

#define N_PTS 4096
#define INV_SQRT2 0.70710678118654752440f

typedef float f32x4 __attribute__((ext_vector_type(4)));
typedef float f32x2 __attribute__((ext_vector_type(2)));
typedef short s16x4 __attribute__((ext_vector_type(4)));
typedef short s16x8 __attribute__((ext_vector_type(8)));
typedef _Float16 f16x2 __attribute__((ext_vector_type(2)));

__device__ inline short f2bf(float x) {
    __hip_bfloat16 h = __float2bfloat16(x);
    return __builtin_bit_cast(short, h);
}

// Truncating pack: 2 f32 -> u32 {bf16(hi),bf16(lo)}. One v_perm_b32.
__device__ inline unsigned pk_trunc(float hi, float lo) {
    return __builtin_amdgcn_perm(__builtin_bit_cast(unsigned, hi),
                                 __builtin_bit_cast(unsigned, lo),
                                 0x07060302u);
}
// Packed relu on 2 bf16 via v_pk_max_f16 (sign-compare; magnitudes never alias f16 NaN).
__device__ inline unsigned pk_relu(unsigned x) {
    f16x2 v = __builtin_bit_cast(f16x2, x);
    f16x2 z = {(_Float16)0.f, (_Float16)0.f};
    return __builtin_bit_cast(unsigned, __builtin_elementwise_max(v, z));
}
__device__ inline float rfl(float x) {
    return __builtin_bit_cast(float, __builtin_amdgcn_readfirstlane(__builtin_bit_cast(int, x)));
}
__device__ inline f32x2 bc2(float s) { return (f32x2){s, s}; }
__device__ inline f32x2 fma2(f32x2 a, f32x2 b, f32x2 c) {
    return __builtin_elementwise_fma(a, b, c);
}

// ---- 16x16x16 bf16 MFMA (Z-gen; layout-chaining shape) ----
#if defined(__has_builtin)
#  if __has_builtin(__builtin_amdgcn_mfma_f32_16x16x16bf16_1k)
#    define MFMA16(a, b, c) __builtin_amdgcn_mfma_f32_16x16x16bf16_1k((a), (b), (c), 0, 0, 0)
#    define HAVE_MFMA16 1
#  elif __has_builtin(__builtin_amdgcn_mfma_f32_16x16x16_bf16)
#    define MFMA16(a, b, c) __builtin_amdgcn_mfma_f32_16x16x16_bf16((a), (b), (c), 0, 0, 0)
#    define HAVE_MFMA16 1
#  endif
#endif
#ifndef HAVE_MFMA16
__device__ inline f32x4 mfma16_asm(s16x4 a, s16x4 b, f32x4 c) {
    asm volatile("s_nop 1\n\tv_mfma_f32_16x16x16_bf16 %0, %1, %2, %0"
                 : "+v"(c) : "v"(a), "v"(b));
    return c;
}
#  define MFMA16(a, b, c) mfma16_asm((a), (b), (c))
#endif

// ---- 16x16x32 bf16 MFMA (acc step; gfx950 full-rate shape) ----
#define MFMA32(a, b, c) __builtin_amdgcn_mfma_f32_16x16x32_bf16((a), (b), (c), 0, 0, 0)

// ---------------------------------------------------------------------------
// Kernel A/D: 64->64->64 MLP + per-group partial stats.
// extra>0: inp has (extra+1) slices of N*64 summed on load (j-split reduce).
// ---------------------------------------------------------------------------
__global__ __launch_bounds__(256) void mlp_gn_kernel(
    const float* __restrict__ inp, int extra,
    const float* __restrict__ W1, const float* __restrict__ b1,
    const float* __restrict__ W2, const float* __restrict__ b2,
    float* __restrict__ pre_out, float* __restrict__ partials)
{
    __shared__ float in_s[4][64];
    __shared__ float h1_s[4][64];
    __shared__ float red_s[4][8];

    const int tid = threadIdx.x;
    const int lane = tid & 63;
    const int wid = tid >> 6;
    const int n0 = blockIdx.x * 4;

    float xin = inp[n0 * 64 + tid];
    for (int s = 1; s <= extra; ++s)
        xin += inp[(size_t)s * (N_PTS * 64) + n0 * 64 + tid];
    in_s[wid][lane] = xin;
    __syncthreads();

    const int c = lane;
    float h = b1[c];
#pragma unroll
    for (int k4 = 0; k4 < 16; ++k4) {
        float4 wv = *(const float4*)&W1[c * 64 + k4 * 4];
        h = fmaf(in_s[wid][k4*4+0], wv.x, h);
        h = fmaf(in_s[wid][k4*4+1], wv.y, h);
        h = fmaf(in_s[wid][k4*4+2], wv.z, h);
        h = fmaf(in_s[wid][k4*4+3], wv.w, h);
    }
    h = (h >= 0.f) ? h : 0.2f * h;
    h1_s[wid][c] = h;
    __syncthreads();

    float g = b2[c];
#pragma unroll
    for (int k4 = 0; k4 < 16; ++k4) {
        float4 wv = *(const float4*)&W2[c * 64 + k4 * 4];
        g = fmaf(h1_s[wid][k4*4+0], wv.x, g);
        g = fmaf(h1_s[wid][k4*4+1], wv.y, g);
        g = fmaf(h1_s[wid][k4*4+2], wv.z, g);
        g = fmaf(h1_s[wid][k4*4+3], wv.w, g);
    }
    g = (g >= 0.f) ? g : 0.2f * g;
    pre_out[n0 * 64 + tid] = g;

    float v = g, v2 = g * g;
#pragma unroll
    for (int m = 1; m < 16; m <<= 1) {
        v  += __shfl_xor(v,  m, 64);
        v2 += __shfl_xor(v2, m, 64);
    }
    if ((lane & 15) == 0) {
        int grp = lane >> 4;
        red_s[wid][grp * 2 + 0] = v;
        red_s[wid][grp * 2 + 1] = v2;
    }
    __syncthreads();
    if (tid < 8) {
        int grp = tid >> 1, which = tid & 1;
        float s = red_s[0][grp*2+which] + red_s[1][grp*2+which]
                + red_s[2][grp*2+which] + red_s[3][grp*2+which];
        partials[blockIdx.x * 8 + grp * 2 + which] = s;
    }
}

// ---------------------------------------------------------------------------
// Kernel B/E: finalize group stats -> per-channel scale/shift.
// ---------------------------------------------------------------------------
__global__ __launch_bounds__(256) void finalize_kernel(
    const float* __restrict__ partials, int nblocks,
    const float* __restrict__ gw, const float* __restrict__ gb,
    float* __restrict__ ss)
{
    __shared__ float red[8][32];
    __shared__ float mean_s[4], inv_s[4];
    const int t = threadIdx.x;
    const int s = t >> 5, slot = t & 31;
    float acc = 0.f;
    for (int b = slot; b < nblocks; b += 32) acc += partials[b * 8 + s];
    red[s][slot] = acc;
    __syncthreads();
    if (t < 8) {
        float v = 0.f;
#pragma unroll
        for (int k = 0; k < 32; ++k) v += red[t][k];
        red[t][0] = v;
    }
    __syncthreads();
    if (t < 4) {
        float S = red[t * 2][0], SS = red[t * 2 + 1][0];
        const float cnt = (float)N_PTS * 16.f;
        float mean = S / cnt;
        float var = SS / cnt - mean * mean;
        mean_s[t] = mean;
        inv_s[t] = rsqrtf(var + 1e-5f);
    }
    __syncthreads();
    if (t < 64) {
        int grp = t >> 4;
        float sc = gw[t] * inv_s[grp];
        ss[t] = sc;
        ss[64 + t] = gb[t] - mean_s[grp] * sc;
    }
}

// ---------------------------------------------------------------------------
// fnt: normalized features bf16 in LINEAR-COALESCED per-tile layout:
//   16B unit index = ((t*2+jp)*4+ht)*64 + hl*4 + g ; shorts [lo*4+r] within.
// Also (blocks 0..15) scaled coords + normal, f32 padded.
// ---------------------------------------------------------------------------
__global__ __launch_bounds__(256) void fnt_kernel(
    const float* __restrict__ f_pre, const float* __restrict__ ss,
    short* __restrict__ fn_sw,
    const float* __restrict__ points, const float* __restrict__ nuv,
    float* __restrict__ ptn4)
{
    const int h = blockIdx.x >> 4;
    const int j = ((blockIdx.x & 15) << 8) + threadIdx.x;
    float v = f_pre[j * 64 + h] * ss[h] + ss[64 + h];
    const int t = j >> 6, jj = j & 63;
    const int jsub = jj >> 4, g = (jj >> 2) & 3, r = jj & 3;
    const int jp = jsub >> 1, lo = jsub & 1;
    const int ht = h >> 4, hl = h & 15;
    const int unit = ((t * 2 + jp) * 4 + ht) * 64 + hl * 4 + g;
    fn_sw[unit * 8 + lo * 4 + r] = f2bf(v);

    if (blockIdx.x < 16) {
        const int pt = blockIdx.x * 256 + threadIdx.x;
        float sx = points[pt*3+0] * INV_SQRT2;
        float sy = points[pt*3+1] * INV_SQRT2;
        float sz = points[pt*3+2] * INV_SQRT2;
        float nx = nuv[pt*9+0], ny = nuv[pt*9+1], nz = nuv[pt*9+2];
        *(float4*)&ptn4[pt*8 + 0] = (float4){sx, sy, sz, 0.f};
        *(float4*)&ptn4[pt*8 + 4] = (float4){nx, ny, nz, 0.f};
    }
}

// ---------------------------------------------------------------------------
// Pairwise: 4 waves/block, 2 i's per wave, NO barriers, fn direct-from-global.
// SOFTWARE-PIPELINED: P_s double-buffered per wave; phase1(t+1) interleaves
// with phase2(t)'s MFMA chain (both wave-local, scheduler free to overlap).
// ---------------------------------------------------------------------------
__global__ __launch_bounds__(256, 4) void pairwise_kernel(
    const float* __restrict__ nuv,
    const float* __restrict__ ptn4,
    const short* __restrict__ fn_sw,
    const float* __restrict__ A1, const float* __restrict__ c1,
    const float* __restrict__ A2, const float* __restrict__ c2,
    float* __restrict__ out_part, int nt, int jshift)
{
    // [4 waves][2 i][2 buf] rows of 768 shorts -> 24 KB
    __shared__ __align__(16) short P_s[16][768];

    const int tid = threadIdx.x;
    const int l = tid & 63;
    const int wid = tid >> 6;
    const int g = l >> 4;
    const int hl = l & 15;

    const int js = blockIdx.x & ((1 << jshift) - 1);
    const int ig = blockIdx.x >> jshift;
    const int i0 = ig * 8 + wid * 2;
    const int tmask = nt - 1;

    // ---- i-pair constants, packed {i0, i1} (wave-uniform -> SGPRs) ----
    f32x2 nv2[9];
#pragma unroll
    for (int k = 0; k < 9; ++k)
        nv2[k] = (f32x2){rfl(nuv[i0 * 9 + k]), rfl(nuv[(i0 + 1) * 9 + k])};
    const f32x2 pix2 = (f32x2){rfl(ptn4[i0*8+0]), rfl(ptn4[(i0+1)*8+0])};
    const f32x2 piy2 = (f32x2){rfl(ptn4[i0*8+1]), rfl(ptn4[(i0+1)*8+1])};
    const f32x2 piz2 = (f32x2){rfl(ptn4[i0*8+2]), rfl(ptn4[(i0+1)*8+2])};

    float a1v[8][3], c1v[8];
#pragma unroll
    for (int cc = 0; cc < 8; ++cc) {
        a1v[cc][0] = A1[cc*3+0]; a1v[cc][1] = A1[cc*3+1]; a1v[cc][2] = A1[cc*3+2];
        c1v[cc] = c1[cc];
    }

    // A2t B-frags (K=16): lane(g,hl): B[k=4g+r][h=ht*16+hl] = A2[h][k]|c2|0
    s16x4 A2sB[4];
#pragma unroll
    for (int ht = 0; ht < 4; ++ht) {
        const int h = ht * 16 + hl;
        s16x4 v;
#pragma unroll
        for (int r = 0; r < 4; ++r) {
            const int cc = 4 * g + r;
            float val = (cc < 8) ? A2[h*8 + cc] : ((cc == 8) ? c2[h] : 0.f);
            v[r] = f2bf(val);
        }
        A2sB[ht] = v;
    }

    f32x4 acc0[4], acc1[4];
#pragma unroll
    for (int ht = 0; ht < 4; ++ht) {
        acc0[ht] = (f32x4){0.f, 0.f, 0.f, 0.f};
        acc1[ht] = (f32x4){0.f, 0.f, 0.f, 0.f};
    }
    const f32x4 Zzero = (f32x4){0.f, 0.f, 0.f, 0.f};

    // per-lane fn offset (shorts): contiguous per instruction
    const int laneoff = (hl * 4 + g) * 8;
    const short* fnb = fn_sw + (size_t)(js * nt) * 4096;
    const float* pbase = ptn4 + (size_t)(js * nt) * 512;

    // ---- phase 1: compute P rows for one tile into P_s buffer `buf` ----
    auto phase1 = [&](int buf, float4 pj, float4 nj) {
        f32x2 dx = bc2(pj.x) - pix2;
        f32x2 dy = bc2(pj.y) - piy2;
        f32x2 dz = bc2(pj.z) - piz2;
        f32x2 s1 = fma2(dz, dz, fma2(dy, dy, dx * dx));
        f32x2 dt = fma2(nv2[2], bc2(nj.z),
                   fma2(nv2[1], bc2(nj.y), nv2[0] * bc2(nj.x)));
        f32x2 t2 = bc2(2.f) - dt;
        f32x2 d2 = (s1 * t2) * t2;
        float w0 = __expf(-d2[0]);
        float w1 = __expf(-d2[1]);
        f32x2 wp = (f32x2){w0, w1};
        f32x2 X0 = fma2(nv2[2], dz, fma2(nv2[1], dy, nv2[0] * dx));
        f32x2 X1 = fma2(nv2[5], dz, fma2(nv2[4], dy, nv2[3] * dx));
        f32x2 X2 = fma2(nv2[8], dz, fma2(nv2[7], dy, nv2[6] * dx));

        f32x2 hv[8];
#pragma unroll
        for (int cc = 0; cc < 8; ++cc) {
            f32x2 tt = fma2(bc2(a1v[cc][2]), X2,
                       fma2(bc2(a1v[cc][1]), X1,
                       fma2(bc2(a1v[cc][0]), X0, bc2(c1v[cc]))));
            hv[cc] = tt * wp;            // relu deferred to packed max
        }
        // i0 row
        {
            int2 ra, rb, rc;
            ra.x = (int)pk_relu(pk_trunc(hv[1][0], hv[0][0]));
            ra.y = (int)pk_relu(pk_trunc(hv[3][0], hv[2][0]));
            rb.x = (int)pk_relu(pk_trunc(hv[5][0], hv[4][0]));
            rb.y = (int)pk_relu(pk_trunc(hv[7][0], hv[6][0]));
            rc.x = (int)(__builtin_bit_cast(unsigned, w0) >> 16);
            rc.y = 0;
            short* rp = &P_s[wid * 4 + 0 + buf][l * 12];
            *(int2*)(rp + 0) = ra;
            *(int2*)(rp + 4) = rb;
            *(int2*)(rp + 8) = rc;
        }
        // i1 row
        {
            int2 ra, rb, rc;
            ra.x = (int)pk_relu(pk_trunc(hv[1][1], hv[0][1]));
            ra.y = (int)pk_relu(pk_trunc(hv[3][1], hv[2][1]));
            rb.x = (int)pk_relu(pk_trunc(hv[5][1], hv[4][1]));
            rb.y = (int)pk_relu(pk_trunc(hv[7][1], hv[6][1]));
            rc.x = (int)(__builtin_bit_cast(unsigned, w1) >> 16);
            rc.y = 0;
            short* rp = &P_s[wid * 4 + 2 + buf][l * 12];
            *(int2*)(rp + 0) = ra;
            *(int2*)(rp + 4) = rb;
            *(int2*)(rp + 8) = rc;
        }
    };

    // ---- prologue: phase1 for tile 0 into buf 0; prefetch pts for tile 1 ----
    {
        float4 pj0 = *(const float4*)&pbase[l * 8];
        float4 nj0 = *(const float4*)&pbase[l * 8 + 4];
        phase1(0, pj0, nj0);
    }
    float4 pj_c = *(const float4*)&pbase[((1 & tmask) * 64 + l) * 8];
    float4 nj_c = *(const float4*)&pbase[((1 & tmask) * 64 + l) * 8 + 4];

    for (int t = 0; t < nt; ++t) {
        const int buf = t & 1;

        // fn fragments for THIS tile (global, L1/L2-hot; issue early)
        const short* bt = fnb + t * 4096;
        s16x8 Fv[2][4];
#pragma unroll
        for (int jp = 0; jp < 2; ++jp)
#pragma unroll
            for (int ht = 0; ht < 4; ++ht)
                Fv[jp][ht] = *(const s16x8*)(bt + (jp * 4 + ht) * 512 + laneoff);

        // pts prefetch for tile t+2 (consumed by next iteration's phase1)
        const int tn = (t + 2) & tmask;
        float4 pj_n = *(const float4*)&pbase[(tn * 64 + l) * 8];
        float4 nj_n = *(const float4*)&pbase[(tn * 64 + l) * 8 + 4];

        // phase1 for NEXT tile into the other buffer (overlaps phase2 below)
        if (t < nt - 1) phase1(buf ^ 1, pj_c, nj_c);

        // ---- phase 2 for tile t from P_s[buf] ----
#pragma unroll
        for (int jp = 0; jp < 2; ++jp) {
            const int j0 = (jp * 2 + 0) * 16 + hl;
            const int j1 = (jp * 2 + 1) * 16 + hl;
            const s16x4 Af00 = *(const s16x4*)&P_s[wid*4 + 0 + buf][j0 * 12 + 4 * g];
            const s16x4 Af01 = *(const s16x4*)&P_s[wid*4 + 0 + buf][j1 * 12 + 4 * g];
            const s16x4 Af10 = *(const s16x4*)&P_s[wid*4 + 2 + buf][j0 * 12 + 4 * g];
            const s16x4 Af11 = *(const s16x4*)&P_s[wid*4 + 2 + buf][j1 * 12 + 4 * g];
#pragma unroll
            for (int ht = 0; ht < 4; ++ht) {
                const s16x8 Fvv = Fv[jp][ht];
                f32x4 Za = MFMA16(Af00, A2sB[ht], Zzero);
                f32x4 Zb = MFMA16(Af01, A2sB[ht], Zzero);
                int4 b0;
                b0.x = (int)pk_relu(pk_trunc(Za[1], Za[0]));
                b0.y = (int)pk_relu(pk_trunc(Za[3], Za[2]));
                b0.z = (int)pk_relu(pk_trunc(Zb[1], Zb[0]));
                b0.w = (int)pk_relu(pk_trunc(Zb[3], Zb[2]));
                acc0[ht] = MFMA32(Fvv, __builtin_bit_cast(s16x8, b0), acc0[ht]);
                f32x4 Zc = MFMA16(Af10, A2sB[ht], Zzero);
                f32x4 Zd = MFMA16(Af11, A2sB[ht], Zzero);
                int4 b1;
                b1.x = (int)pk_relu(pk_trunc(Zc[1], Zc[0]));
                b1.y = (int)pk_relu(pk_trunc(Zc[3], Zc[2]));
                b1.z = (int)pk_relu(pk_trunc(Zd[1], Zd[0]));
                b1.w = (int)pk_relu(pk_trunc(Zd[3], Zd[2]));
                acc1[ht] = MFMA32(Fvv, __builtin_bit_cast(s16x8, b1), acc1[ht]);
            }
        }
        pj_c = pj_n; nj_c = nj_n;
    }

    asm volatile("s_nop 7\n\ts_nop 7" ::: );

    // diag extraction: lane with g == hl>>2 holds diag element (reg r = hl&3)
    if (g == (hl >> 2)) {
        const int r = hl & 3;
        float* ob = out_part + (size_t)js * (N_PTS * 64);
#pragma unroll
        for (int ht = 0; ht < 4; ++ht) {
            float v0 = (r == 0) ? acc0[ht][0] : (r == 1) ? acc0[ht][1]
                     : (r == 2) ? acc0[ht][2] : acc0[ht][3];
            float v1 = (r == 0) ? acc1[ht][0] : (r == 1) ? acc1[ht][1]
                     : (r == 2) ? acc1[ht][2] : acc1[ht][3];
            ob[(i0 + 0) * 64 + ht * 16 + hl] = v0;
            ob[(i0 + 1) * 64 + ht * 16 + hl] = v1;
        }
    }
}

// ---------------------------------------------------------------------------
// Kernel F: apply output groupnorm affine.
// ---------------------------------------------------------------------------
__global__ __launch_bounds__(256) void apply_kernel(
    const float* __restrict__ pre, const float* __restrict__ ss,
    float* __restrict__ out)
{
    int idx = blockIdx.x * 256 + threadIdx.x;
    int c = idx & 63;
    out[idx] = pre[idx] * ss[c] + ss[64 + c];
}

// ---------------------------------------------------------------------------
extern "C" void kernel_launch(void* const* d_in, const int* in_sizes, int n_in,
                              void* d_out, int out_size, void* d_ws, size_t ws_size,
                              hipStream_t stream) {
    const float* points   = (const float*)d_in[0];
    const float* nuv      = (const float*)d_in[1];
    const float* features = (const float*)d_in[2];
    const float* W_in1    = (const float*)d_in[3];
    const float* b_in1    = (const float*)d_in[4];
    const float* W_in2    = (const float*)d_in[5];
    const float* b_in2    = (const float*)d_in[6];
    const float* gn_in_w  = (const float*)d_in[7];
    const float* gn_in_b  = (const float*)d_in[8];
    const float* A1       = (const float*)d_in[9];
    const float* c1       = (const float*)d_in[10];
    const float* A2       = (const float*)d_in[11];
    const float* c2       = (const float*)d_in[12];
    const float* W_out1   = (const float*)d_in[13];
    const float* b_out1   = (const float*)d_in[14];
    const float* W_out2   = (const float*)d_in[15];
    const float* b_out2   = (const float*)d_in[16];
    const float* gn_out_w = (const float*)d_in[17];
    const float* gn_out_b = (const float*)d_in[18];

    // j-split: 4 if workspace allows, else 2.
    const size_t MB = 1048576;
    const int JS = (ws_size >= 5 * MB) ? 4 : 2;
    const int jshift = (JS == 4) ? 2 : 1;
    const int nt = 64 / JS;
    const size_t op_bytes = (size_t)JS * N_PTS * 64 * 4;

    char* ws = (char*)d_ws;
    float* out_part = (float*)(ws + 0);                 // JS MB
    float* f_pre    = (float*)(ws + 0);                 // 1 MB alias (dead early)
    float* g_pre    = (float*)(ws + 0);                 // 1 MB alias (late, safe)
    short* fn_sw    = (short*)(ws + op_bytes);          // 512 KB
    float* ptn4     = (float*)(ws + op_bytes + 524288); // 128 KB
    char*  tail     = ws + op_bytes + 524288 + 131072;
    float* part_in  = (float*)(tail);                   // 32 KB
    float* part_out = (float*)(tail + 32768);           // 32 KB
    float* ss_in    = (float*)(tail + 65536);           // 512 B
    float* ss_out   = (float*)(tail + 66048);           // 512 B

    float* outp = (float*)d_out;

    mlp_gn_kernel<<<1024, 256, 0, stream>>>(features, 0, W_in1, b_in1,
                                            W_in2, b_in2, f_pre, part_in);
    finalize_kernel<<<1, 256, 0, stream>>>(part_in, 1024, gn_in_w, gn_in_b, ss_in);
    fnt_kernel<<<1024, 256, 0, stream>>>(f_pre, ss_in, fn_sw, points, nuv, ptn4);

    pairwise_kernel<<<512 * JS, 256, 0, stream>>>(nuv, ptn4, fn_sw,
                                                  A1, c1, A2, c2, out_part,
                                                  nt, jshift);

    mlp_gn_kernel<<<1024, 256, 0, stream>>>(out_part, JS - 1, W_out1, b_out1,
                                            W_out2, b_out2, g_pre, part_out);
    finalize_kernel<<<1, 256, 0, stream>>>(part_out, 1024, gn_out_w, gn_out_b, ss_out);

    apply_kernel<<<1024, 256, 0, stream>>>(g_pre, ss_out, outp);
}

// Round 15
// 166.361 us; speedup vs baseline: 1.0519x; 1.0519x over previous
//
#include <hip/hip_runtime.h>
#include <hip/hip_bf16.h>
#include <math.h>

#define N_PTS 4096
#define INV_SQRT2 0.70710678118654752440f

typedef float f32x4 __attribute__((ext_vector_type(4)));
typedef float f32x2 __attribute__((ext_vector_type(2)));
typedef short s16x4 __attribute__((ext_vector_type(4)));
typedef short s16x8 __attribute__((ext_vector_type(8)));
typedef _Float16 f16x2 __attribute__((ext_vector_type(2)));

__device__ inline short f2bf(float x) {
    __hip_bfloat16 h = __float2bfloat16(x);
    return __builtin_bit_cast(short, h);
}

// Truncating pack: 2 f32 -> u32 {bf16(hi),bf16(lo)}. One v_perm_b32.
__device__ inline unsigned pk_trunc(float hi, float lo) {
    return __builtin_amdgcn_perm(__builtin_bit_cast(unsigned, hi),
                                 __builtin_bit_cast(unsigned, lo),
                                 0x07060302u);
}
// Packed relu on 2 bf16 via v_pk_max_f16 (sign-compare; magnitudes never alias f16 NaN).
__device__ inline unsigned pk_relu(unsigned x) {
    f16x2 v = __builtin_bit_cast(f16x2, x);
    f16x2 z = {(_Float16)0.f, (_Float16)0.f};
    return __builtin_bit_cast(unsigned, __builtin_elementwise_max(v, z));
}
__device__ inline float rfl(float x) {
    return __builtin_bit_cast(float, __builtin_amdgcn_readfirstlane(__builtin_bit_cast(int, x)));
}
__device__ inline f32x2 bc2(float s) { return (f32x2){s, s}; }
__device__ inline f32x2 fma2(f32x2 a, f32x2 b, f32x2 c) {
    return __builtin_elementwise_fma(a, b, c);
}

// ---- 16x16x16 bf16 MFMA (Z-gen; layout-chaining shape) ----
#if defined(__has_builtin)
#  if __has_builtin(__builtin_amdgcn_mfma_f32_16x16x16bf16_1k)
#    define MFMA16(a, b, c) __builtin_amdgcn_mfma_f32_16x16x16bf16_1k((a), (b), (c), 0, 0, 0)
#    define HAVE_MFMA16 1
#  elif __has_builtin(__builtin_amdgcn_mfma_f32_16x16x16_bf16)
#    define MFMA16(a, b, c) __builtin_amdgcn_mfma_f32_16x16x16_bf16((a), (b), (c), 0, 0, 0)
#    define HAVE_MFMA16 1
#  endif
#endif
#ifndef HAVE_MFMA16
__device__ inline f32x4 mfma16_asm(s16x4 a, s16x4 b, f32x4 c) {
    asm volatile("s_nop 1\n\tv_mfma_f32_16x16x16_bf16 %0, %1, %2, %0"
                 : "+v"(c) : "v"(a), "v"(b));
    return c;
}
#  define MFMA16(a, b, c) mfma16_asm((a), (b), (c))
#endif

// ---- 16x16x32 bf16 MFMA (acc step; gfx950 full-rate shape) ----
#define MFMA32(a, b, c) __builtin_amdgcn_mfma_f32_16x16x32_bf16((a), (b), (c), 0, 0, 0)

// ---------------------------------------------------------------------------
// Kernel A/D: 64->64->64 MLP + per-group partial stats.
// extra>0: inp has (extra+1) slices of N*64 summed on load (j-split reduce).
// ---------------------------------------------------------------------------
__global__ __launch_bounds__(256) void mlp_gn_kernel(
    const float* __restrict__ inp, int extra,
    const float* __restrict__ W1, const float* __restrict__ b1,
    const float* __restrict__ W2, const float* __restrict__ b2,
    float* __restrict__ pre_out, float* __restrict__ partials)
{
    __shared__ float in_s[4][64];
    __shared__ float h1_s[4][64];
    __shared__ float red_s[4][8];

    const int tid = threadIdx.x;
    const int lane = tid & 63;
    const int wid = tid >> 6;
    const int n0 = blockIdx.x * 4;

    float xin = inp[n0 * 64 + tid];
    for (int s = 1; s <= extra; ++s)
        xin += inp[(size_t)s * (N_PTS * 64) + n0 * 64 + tid];
    in_s[wid][lane] = xin;
    __syncthreads();

    const int c = lane;
    float h = b1[c];
#pragma unroll
    for (int k4 = 0; k4 < 16; ++k4) {
        float4 wv = *(const float4*)&W1[c * 64 + k4 * 4];
        h = fmaf(in_s[wid][k4*4+0], wv.x, h);
        h = fmaf(in_s[wid][k4*4+1], wv.y, h);
        h = fmaf(in_s[wid][k4*4+2], wv.z, h);
        h = fmaf(in_s[wid][k4*4+3], wv.w, h);
    }
    h = (h >= 0.f) ? h : 0.2f * h;
    h1_s[wid][c] = h;
    __syncthreads();

    float g = b2[c];
#pragma unroll
    for (int k4 = 0; k4 < 16; ++k4) {
        float4 wv = *(const float4*)&W2[c * 64 + k4 * 4];
        g = fmaf(h1_s[wid][k4*4+0], wv.x, g);
        g = fmaf(h1_s[wid][k4*4+1], wv.y, g);
        g = fmaf(h1_s[wid][k4*4+2], wv.z, g);
        g = fmaf(h1_s[wid][k4*4+3], wv.w, g);
    }
    g = (g >= 0.f) ? g : 0.2f * g;
    pre_out[n0 * 64 + tid] = g;

    float v = g, v2 = g * g;
#pragma unroll
    for (int m = 1; m < 16; m <<= 1) {
        v  += __shfl_xor(v,  m, 64);
        v2 += __shfl_xor(v2, m, 64);
    }
    if ((lane & 15) == 0) {
        int grp = lane >> 4;
        red_s[wid][grp * 2 + 0] = v;
        red_s[wid][grp * 2 + 1] = v2;
    }
    __syncthreads();
    if (tid < 8) {
        int grp = tid >> 1, which = tid & 1;
        float s = red_s[0][grp*2+which] + red_s[1][grp*2+which]
                + red_s[2][grp*2+which] + red_s[3][grp*2+which];
        partials[blockIdx.x * 8 + grp * 2 + which] = s;
    }
}

// ---------------------------------------------------------------------------
// Kernel B/E: finalize group stats -> per-channel scale/shift.
// ---------------------------------------------------------------------------
__global__ __launch_bounds__(256) void finalize_kernel(
    const float* __restrict__ partials, int nblocks,
    const float* __restrict__ gw, const float* __restrict__ gb,
    float* __restrict__ ss)
{
    __shared__ float red[8][32];
    __shared__ float mean_s[4], inv_s[4];
    const int t = threadIdx.x;
    const int s = t >> 5, slot = t & 31;
    float acc = 0.f;
    for (int b = slot; b < nblocks; b += 32) acc += partials[b * 8 + s];
    red[s][slot] = acc;
    __syncthreads();
    if (t < 8) {
        float v = 0.f;
#pragma unroll
        for (int k = 0; k < 32; ++k) v += red[t][k];
        red[t][0] = v;
    }
    __syncthreads();
    if (t < 4) {
        float S = red[t * 2][0], SS = red[t * 2 + 1][0];
        const float cnt = (float)N_PTS * 16.f;
        float mean = S / cnt;
        float var = SS / cnt - mean * mean;
        mean_s[t] = mean;
        inv_s[t] = rsqrtf(var + 1e-5f);
    }
    __syncthreads();
    if (t < 64) {
        int grp = t >> 4;
        float sc = gw[t] * inv_s[grp];
        ss[t] = sc;
        ss[64 + t] = gb[t] - mean_s[grp] * sc;
    }
}

// ---------------------------------------------------------------------------
// fnt: normalized features bf16 in LINEAR-COALESCED per-tile layout:
//   16B unit index = ((t*2+jp)*4+ht)*64 + hl*4 + g ; shorts [lo*4+r] within.
//   (jp=jsub>>1, lo=jsub&1, g=(jj>>2)&3, r=jj&3; h=ht*16+hl)
// One pairwise read instruction (fixed jp,ht) covers a contiguous 1KB block.
// Also (blocks 0..15) scaled coords + normal, f32 padded.
// ---------------------------------------------------------------------------
__global__ __launch_bounds__(256) void fnt_kernel(
    const float* __restrict__ f_pre, const float* __restrict__ ss,
    short* __restrict__ fn_sw,
    const float* __restrict__ points, const float* __restrict__ nuv,
    float* __restrict__ ptn4)
{
    const int h = blockIdx.x >> 4;
    const int j = ((blockIdx.x & 15) << 8) + threadIdx.x;
    float v = f_pre[j * 64 + h] * ss[h] + ss[64 + h];
    const int t = j >> 6, jj = j & 63;
    const int jsub = jj >> 4, g = (jj >> 2) & 3, r = jj & 3;
    const int jp = jsub >> 1, lo = jsub & 1;
    const int ht = h >> 4, hl = h & 15;
    const int unit = ((t * 2 + jp) * 4 + ht) * 64 + hl * 4 + g;
    fn_sw[unit * 8 + lo * 4 + r] = f2bf(v);

    if (blockIdx.x < 16) {
        const int pt = blockIdx.x * 256 + threadIdx.x;
        float sx = points[pt*3+0] * INV_SQRT2;
        float sy = points[pt*3+1] * INV_SQRT2;
        float sz = points[pt*3+2] * INV_SQRT2;
        float nx = nuv[pt*9+0], ny = nuv[pt*9+1], nz = nuv[pt*9+2];
        *(float4*)&ptn4[pt*8 + 0] = (float4){sx, sy, sz, 0.f};
        *(float4*)&ptn4[pt*8 + 4] = (float4){nx, ny, nz, 0.f};
    }
}

// ---------------------------------------------------------------------------
// Pairwise: 4 waves/block, 2 i's per wave. fn read DIRECTLY from global
// (L1/L2-resident, coalesced 1KB per instruction) -> no FS LDS, no barriers;
// LDS holds only the wave-local P_s. Z-gen = MFMA16; acc = MFMA32 (K=32).
// ---------------------------------------------------------------------------
__global__ __launch_bounds__(256, 4) void pairwise_kernel(
    const float* __restrict__ nuv,
    const float* __restrict__ ptn4,
    const short* __restrict__ fn_sw,
    const float* __restrict__ A1, const float* __restrict__ c1,
    const float* __restrict__ A2, const float* __restrict__ c2,
    float* __restrict__ out_part, int nt, int jshift)
{
    __shared__ __align__(16) short P_s[8][768];   // 12 KB (4 waves x 2 i)

    const int tid = threadIdx.x;
    const int l = tid & 63;
    const int wid = tid >> 6;
    const int g = l >> 4;
    const int hl = l & 15;

    const int js = blockIdx.x & ((1 << jshift) - 1);
    const int ig = blockIdx.x >> jshift;
    const int i0 = ig * 8 + wid * 2;
    const int tmask = nt - 1;

    // ---- i-pair constants, packed {i0, i1} ----
    f32x2 nv2[9];
#pragma unroll
    for (int k = 0; k < 9; ++k)
        nv2[k] = (f32x2){rfl(nuv[i0 * 9 + k]), rfl(nuv[(i0 + 1) * 9 + k])};
    const f32x2 pix2 = (f32x2){rfl(ptn4[i0*8+0]), rfl(ptn4[(i0+1)*8+0])};
    const f32x2 piy2 = (f32x2){rfl(ptn4[i0*8+1]), rfl(ptn4[(i0+1)*8+1])};
    const f32x2 piz2 = (f32x2){rfl(ptn4[i0*8+2]), rfl(ptn4[(i0+1)*8+2])};

    float a1v[8][3], c1v[8];
#pragma unroll
    for (int cc = 0; cc < 8; ++cc) {
        a1v[cc][0] = A1[cc*3+0]; a1v[cc][1] = A1[cc*3+1]; a1v[cc][2] = A1[cc*3+2];
        c1v[cc] = c1[cc];
    }

    // A2t B-frags (K=16): lane(g,hl): B[k=4g+r][h=ht*16+hl] = A2[h][k]|c2|0
    s16x4 A2sB[4];
#pragma unroll
    for (int ht = 0; ht < 4; ++ht) {
        const int h = ht * 16 + hl;
        s16x4 v;
#pragma unroll
        for (int r = 0; r < 4; ++r) {
            const int cc = 4 * g + r;
            float val = (cc < 8) ? A2[h*8 + cc] : ((cc == 8) ? c2[h] : 0.f);
            v[r] = f2bf(val);
        }
        A2sB[ht] = v;
    }

    f32x4 acc0[4], acc1[4];
#pragma unroll
    for (int ht = 0; ht < 4; ++ht) {
        acc0[ht] = (f32x4){0.f, 0.f, 0.f, 0.f};
        acc1[ht] = (f32x4){0.f, 0.f, 0.f, 0.f};
    }
    const f32x4 Zzero = (f32x4){0.f, 0.f, 0.f, 0.f};

    // per-lane fn offset (shorts): contiguous per instruction
    const int laneoff = (hl * 4 + g) * 8;
    const short* fnb = fn_sw + (size_t)(js * nt) * 4096;
    const float* pbase = ptn4 + (size_t)(js * nt) * 512;

    float4 pj_c = *(const float4*)&pbase[l * 8];
    float4 nj_c = *(const float4*)&pbase[l * 8 + 4];

    for (int t = 0; t < nt; ++t) {
        // ---- fn fragments for this tile, direct from global (L1/L2-hot) ----
        const short* bt = fnb + t * 4096;
        s16x8 Fv[2][4];
#pragma unroll
        for (int jp = 0; jp < 2; ++jp)
#pragma unroll
            for (int ht = 0; ht < 4; ++ht)
                Fv[jp][ht] = *(const s16x8*)(bt + (jp * 4 + ht) * 512 + laneoff);

        const int tn = (t + 1) & tmask;
        float4 pj_n = *(const float4*)&pbase[(tn * 64 + l) * 8];
        float4 nj_n = *(const float4*)&pbase[(tn * 64 + l) * 8 + 4];

        // ---- phase 1 (packed over the i-pair): lane l owns j = tile*64+l ----
        {
            f32x2 dx = bc2(pj_c.x) - pix2;
            f32x2 dy = bc2(pj_c.y) - piy2;
            f32x2 dz = bc2(pj_c.z) - piz2;
            f32x2 s1 = fma2(dz, dz, fma2(dy, dy, dx * dx));
            f32x2 dt = fma2(nv2[2], bc2(nj_c.z),
                       fma2(nv2[1], bc2(nj_c.y), nv2[0] * bc2(nj_c.x)));
            f32x2 t2 = bc2(2.f) - dt;
            f32x2 d2 = (s1 * t2) * t2;
            float w0 = __expf(-d2[0]);
            float w1 = __expf(-d2[1]);
            f32x2 wp = (f32x2){w0, w1};
            f32x2 X0 = fma2(nv2[2], dz, fma2(nv2[1], dy, nv2[0] * dx));
            f32x2 X1 = fma2(nv2[5], dz, fma2(nv2[4], dy, nv2[3] * dx));
            f32x2 X2 = fma2(nv2[8], dz, fma2(nv2[7], dy, nv2[6] * dx));

            f32x2 hv[8];
#pragma unroll
            for (int cc = 0; cc < 8; ++cc) {
                f32x2 tt = fma2(bc2(a1v[cc][2]), X2,
                           fma2(bc2(a1v[cc][1]), X1,
                           fma2(bc2(a1v[cc][0]), X0, bc2(c1v[cc]))));
                hv[cc] = tt * wp;            // relu deferred to packed max
            }
            // i0 row
            {
                int2 ra, rb, rc;
                ra.x = (int)pk_relu(pk_trunc(hv[1][0], hv[0][0]));
                ra.y = (int)pk_relu(pk_trunc(hv[3][0], hv[2][0]));
                rb.x = (int)pk_relu(pk_trunc(hv[5][0], hv[4][0]));
                rb.y = (int)pk_relu(pk_trunc(hv[7][0], hv[6][0]));
                rc.x = (int)(__builtin_bit_cast(unsigned, w0) >> 16);
                rc.y = 0;
                short* rp = &P_s[wid * 2 + 0][l * 12];
                *(int2*)(rp + 0) = ra;
                *(int2*)(rp + 4) = rb;
                *(int2*)(rp + 8) = rc;
            }
            // i1 row
            {
                int2 ra, rb, rc;
                ra.x = (int)pk_relu(pk_trunc(hv[1][1], hv[0][1]));
                ra.y = (int)pk_relu(pk_trunc(hv[3][1], hv[2][1]));
                rb.x = (int)pk_relu(pk_trunc(hv[5][1], hv[4][1]));
                rb.y = (int)pk_relu(pk_trunc(hv[7][1], hv[6][1]));
                rc.x = (int)(__builtin_bit_cast(unsigned, w1) >> 16);
                rc.y = 0;
                short* rp = &P_s[wid * 2 + 1][l * 12];
                *(int2*)(rp + 0) = ra;
                *(int2*)(rp + 4) = rb;
                *(int2*)(rp + 8) = rc;
            }
        }
        // no barrier anywhere: P_s is wave-local; fn/pts come from global.

        // ---- phase 2: Z-gen (MFMA16) + acc (MFMA32, 2 jsubs K-interleaved) ----
#pragma unroll
        for (int jp = 0; jp < 2; ++jp) {
            const int j0 = (jp * 2 + 0) * 16 + hl;
            const int j1 = (jp * 2 + 1) * 16 + hl;
            const s16x4 Af00 = *(const s16x4*)&P_s[wid*2+0][j0 * 12 + 4 * g];
            const s16x4 Af01 = *(const s16x4*)&P_s[wid*2+0][j1 * 12 + 4 * g];
            const s16x4 Af10 = *(const s16x4*)&P_s[wid*2+1][j0 * 12 + 4 * g];
            const s16x4 Af11 = *(const s16x4*)&P_s[wid*2+1][j1 * 12 + 4 * g];
#pragma unroll
            for (int ht = 0; ht < 4; ++ht) {
                const s16x8 Fvv = Fv[jp][ht];
                f32x4 Za = MFMA16(Af00, A2sB[ht], Zzero);
                f32x4 Zb = MFMA16(Af01, A2sB[ht], Zzero);
                int4 b0;
                b0.x = (int)pk_relu(pk_trunc(Za[1], Za[0]));
                b0.y = (int)pk_relu(pk_trunc(Za[3], Za[2]));
                b0.z = (int)pk_relu(pk_trunc(Zb[1], Zb[0]));
                b0.w = (int)pk_relu(pk_trunc(Zb[3], Zb[2]));
                acc0[ht] = MFMA32(Fvv, __builtin_bit_cast(s16x8, b0), acc0[ht]);
                f32x4 Zc = MFMA16(Af10, A2sB[ht], Zzero);
                f32x4 Zd = MFMA16(Af11, A2sB[ht], Zzero);
                int4 b1;
                b1.x = (int)pk_relu(pk_trunc(Zc[1], Zc[0]));
                b1.y = (int)pk_relu(pk_trunc(Zc[3], Zc[2]));
                b1.z = (int)pk_relu(pk_trunc(Zd[1], Zd[0]));
                b1.w = (int)pk_relu(pk_trunc(Zd[3], Zd[2]));
                acc1[ht] = MFMA32(Fvv, __builtin_bit_cast(s16x8, b1), acc1[ht]);
            }
        }
        pj_c = pj_n; nj_c = nj_n;
    }

    asm volatile("s_nop 7\n\ts_nop 7" ::: );

    // diag extraction: lane with g == hl>>2 holds diag element (reg r = hl&3)
    if (g == (hl >> 2)) {
        const int r = hl & 3;
        float* ob = out_part + (size_t)js * (N_PTS * 64);
#pragma unroll
        for (int ht = 0; ht < 4; ++ht) {
            float v0 = (r == 0) ? acc0[ht][0] : (r == 1) ? acc0[ht][1]
                     : (r == 2) ? acc0[ht][2] : acc0[ht][3];
            float v1 = (r == 0) ? acc1[ht][0] : (r == 1) ? acc1[ht][1]
                     : (r == 2) ? acc1[ht][2] : acc1[ht][3];
            ob[(i0 + 0) * 64 + ht * 16 + hl] = v0;
            ob[(i0 + 1) * 64 + ht * 16 + hl] = v1;
        }
    }
}

// ---------------------------------------------------------------------------
// Kernel F: apply output groupnorm affine.
// ---------------------------------------------------------------------------
__global__ __launch_bounds__(256) void apply_kernel(
    const float* __restrict__ pre, const float* __restrict__ ss,
    float* __restrict__ out)
{
    int idx = blockIdx.x * 256 + threadIdx.x;
    int c = idx & 63;
    out[idx] = pre[idx] * ss[c] + ss[64 + c];
}

// ---------------------------------------------------------------------------
extern "C" void kernel_launch(void* const* d_in, const int* in_sizes, int n_in,
                              void* d_out, int out_size, void* d_ws, size_t ws_size,
                              hipStream_t stream) {
    const float* points   = (const float*)d_in[0];
    const float* nuv      = (const float*)d_in[1];
    const float* features = (const float*)d_in[2];
    const float* W_in1    = (const float*)d_in[3];
    const float* b_in1    = (const float*)d_in[4];
    const float* W_in2    = (const float*)d_in[5];
    const float* b_in2    = (const float*)d_in[6];
    const float* gn_in_w  = (const float*)d_in[7];
    const float* gn_in_b  = (const float*)d_in[8];
    const float* A1       = (const float*)d_in[9];
    const float* c1       = (const float*)d_in[10];
    const float* A2       = (const float*)d_in[11];
    const float* c2       = (const float*)d_in[12];
    const float* W_out1   = (const float*)d_in[13];
    const float* b_out1   = (const float*)d_in[14];
    const float* W_out2   = (const float*)d_in[15];
    const float* b_out2   = (const float*)d_in[16];
    const float* gn_out_w = (const float*)d_in[17];
    const float* gn_out_b = (const float*)d_in[18];

    // j-split: 4 if workspace allows, else 2.
    const size_t MB = 1048576;
    const int JS = (ws_size >= 5 * MB) ? 4 : 2;
    const int jshift = (JS == 4) ? 2 : 1;
    const int nt = 64 / JS;
    const size_t op_bytes = (size_t)JS * N_PTS * 64 * 4;

    char* ws = (char*)d_ws;
    float* out_part = (float*)(ws + 0);                 // JS MB
    float* f_pre    = (float*)(ws + 0);                 // 1 MB alias (dead early)
    float* g_pre    = (float*)(ws + 0);                 // 1 MB alias (late, safe)
    short* fn_sw    = (short*)(ws + op_bytes);          // 512 KB
    float* ptn4     = (float*)(ws + op_bytes + 524288); // 128 KB
    char*  tail     = ws + op_bytes + 524288 + 131072;
    float* part_in  = (float*)(tail);                   // 32 KB
    float* part_out = (float*)(tail + 32768);           // 32 KB
    float* ss_in    = (float*)(tail + 65536);           // 512 B
    float* ss_out   = (float*)(tail + 66048);           // 512 B

    float* outp = (float*)d_out;

    mlp_gn_kernel<<<1024, 256, 0, stream>>>(features, 0, W_in1, b_in1,
                                            W_in2, b_in2, f_pre, part_in);
    finalize_kernel<<<1, 256, 0, stream>>>(part_in, 1024, gn_in_w, gn_in_b, ss_in);
    fnt_kernel<<<1024, 256, 0, stream>>>(f_pre, ss_in, fn_sw, points, nuv, ptn4);

    pairwise_kernel<<<512 * JS, 256, 0, stream>>>(nuv, ptn4, fn_sw,
                                                  A1, c1, A2, c2, out_part,
                                                  nt, jshift);

    mlp_gn_kernel<<<1024, 256, 0, stream>>>(out_part, JS - 1, W_out1, b_out1,
                                            W_out2, b_out2, g_pre, part_out);
    finalize_kernel<<<1, 256, 0, stream>>>(part_out, 1024, gn_out_w, gn_out_b, ss_out);

    apply_kernel<<<1024, 256, 0, stream>>>(g_pre, ss_out, outp);
}